// Round 15
// baseline (489.530 us; speedup 1.0000x reference)
//
#include <hip/hip_runtime.h>
#include <hip/hip_bf16.h>

#define N_NODES 50000
#define N_REL   4
#define N_EDGES 500000
#define EMB     128
#define HID     128
#define OUTD    64
#define SLICES  32
#define EPS     (N_EDGES / SLICES)   // 15625 edges per slice (exact)
#define CHUNKN  25000                // nodes per chunk (2 chunks)
#define CHUNKW  12500                // packed u32 per chunk (2 x u16)
#define NBLK2   98                   // ceil(50000 / 512) scan1 blocks per rel

typedef __attribute__((ext_vector_type(8))) short short8v;   // 8 bf16 = 4 VGPR
typedef __attribute__((ext_vector_type(4))) float float4v;   // mfma acc

__device__ __forceinline__ unsigned short f2bf(float f) {   // RNE bf16 pack
    unsigned u = __float_as_uint(f);
    u = (u + 0x7fffu + ((u >> 16) & 1u)) >> 16;
    return (unsigned short)u;
}
__device__ __forceinline__ float bf2f(unsigned v) {
    return __uint_as_float(v << 16);
}

// ---- 0) prep: fused emb->bf16 cvt + W1/W2 fragment packs --------------------
__global__ void prep_kernel(const float* __restrict__ emb,
                            const float* __restrict__ W1,
                            const float* __restrict__ W2,
                            unsigned short* __restrict__ embb,
                            unsigned short* __restrict__ W1p,
                            unsigned short* __restrict__ W2p) {
    int b = blockIdx.x, t = threadIdx.x;
    if (b < 6250) {                            // cvt: 1.6M float4
        int i = b * 256 + t;
        float4 v = *(const float4*)&emb[(size_t)i * 4];
        ushort4 o;
        o.x = f2bf(v.x); o.y = f2bf(v.y); o.z = f2bf(v.z); o.w = f2bf(v.w);
        *(ushort4*)&embb[(size_t)i * 4] = o;
    } else if (b < 6282) {                     // packW1: 8192 fragments
        int idx = (b - 6250) * 256 + t;
        int l = idx & 63, ct = (idx >> 6) & 7, ks = idx >> 9;
        int n = ct * 16 + (l & 15);
        int k0 = ks * 32 + (l >> 4) * 8;
        ushort4 o0, o1;
        o0.x = f2bf(W1[(size_t)(k0 + 0) * 128 + n]);
        o0.y = f2bf(W1[(size_t)(k0 + 1) * 128 + n]);
        o0.z = f2bf(W1[(size_t)(k0 + 2) * 128 + n]);
        o0.w = f2bf(W1[(size_t)(k0 + 3) * 128 + n]);
        o1.x = f2bf(W1[(size_t)(k0 + 4) * 128 + n]);
        o1.y = f2bf(W1[(size_t)(k0 + 5) * 128 + n]);
        o1.z = f2bf(W1[(size_t)(k0 + 6) * 128 + n]);
        o1.w = f2bf(W1[(size_t)(k0 + 7) * 128 + n]);
        *(ushort4*)&W1p[(size_t)idx * 8]     = o0;
        *(ushort4*)&W1p[(size_t)idx * 8 + 4] = o1;
    } else {                                   // packW2: 4096 fragments
        int idx = (b - 6282) * 256 + t;
        int l = idx & 63, ct = (idx >> 6) & 15, ks = idx >> 10;
        int n = ct * 16 + (l & 15);
        int r = n >> 6, cc = n & 63;
        int k0 = ks * 32 + (l >> 4) * 8;
        ushort4 o0, o1;
        o0.x = f2bf(W2[((size_t)r * 128 + k0 + 0) * 64 + cc]);
        o0.y = f2bf(W2[((size_t)r * 128 + k0 + 1) * 64 + cc]);
        o0.z = f2bf(W2[((size_t)r * 128 + k0 + 2) * 64 + cc]);
        o0.w = f2bf(W2[((size_t)r * 128 + k0 + 3) * 64 + cc]);
        o1.x = f2bf(W2[((size_t)r * 128 + k0 + 4) * 64 + cc]);
        o1.y = f2bf(W2[((size_t)r * 128 + k0 + 5) * 64 + cc]);
        o1.z = f2bf(W2[((size_t)r * 128 + k0 + 6) * 64 + cc]);
        o1.w = f2bf(W2[((size_t)r * 128 + k0 + 7) * 64 + cc]);
        *(ushort4*)&W2p[(size_t)idx * 8]     = o0;
        *(ushort4*)&W2p[(size_t)idx * 8 + 4] = o1;
    }
}

// ---- 1) hist: per-slice LDS count histograms (no global atomics) ------------
__global__ __launch_bounds__(512) void hist_kernel(
    const int* __restrict__ src, const int* __restrict__ dst,
    unsigned* __restrict__ cnt_dst, unsigned* __restrict__ cnt_src) {
    const int s = blockIdx.x;
    const int ch = blockIdx.y;
    const int z = blockIdx.z;
    const int r = z & 3;
    const bool do_dst = (z < 4);
    const int t = threadIdx.x;
    __shared__ unsigned bins[CHUNKW];          // 50 KB: 25000 x u16 packed
    for (int i = t; i < CHUNKW; i += 512) bins[i] = 0;
    __syncthreads();
    const int* col = do_dst ? dst : src;
    const int c0 = ch * CHUNKN;
    for (int e = s * EPS + t; e < (s + 1) * EPS; e += 512) {
        unsigned dl = (unsigned)(col[(size_t)r * N_EDGES + e] - c0);
        if (dl < CHUNKN)
            atomicAdd(&bins[dl >> 1], 1u << ((dl & 1) * 16));
    }
    __syncthreads();
    unsigned* out = (do_dst ? cnt_dst : cnt_src)
                  + (((size_t)s * N_REL + r) * 2 + ch) * CHUNKW;
    for (int i = t; i < CHUNKW; i += 512) out[i] = bins[i];
}

// ---- 2a) scan1: slice-reduce + in-place slice-prefix + norms + block scan ---
__global__ __launch_bounds__(256) void scan1_kernel(
    unsigned* __restrict__ cnt_dst, const unsigned* __restrict__ cnt_src,
    float* __restrict__ nsrc, float* __restrict__ ndst,
    int* __restrict__ offs, int* __restrict__ bsum) {
    const int r = blockIdx.y;
    const int blk = blockIdx.x;
    const int t = threadIdx.x;
    const int pair = blk * 256 + t;            // 0 .. 24999
    int d0 = 0, d1 = 0;
    if (pair < CHUNKN) {
        int ch = (2 * pair) / CHUNKN;          // 0 or 1
        int i = pair - ch * CHUNKW;
        unsigned run0 = 0, run1 = 0;
#pragma unroll
        for (int s = 0; s < SLICES; ++s) {
            size_t idx = (((size_t)s * N_REL + r) * 2 + ch) * CHUNKW + i;
            unsigned v = cnt_dst[idx];
            cnt_dst[idx] = run0 | (run1 << 16); // exclusive slice-prefix (packed)
            run0 += v & 0xffffu;
            run1 += v >> 16;
        }
        d0 = (int)run0; d1 = (int)run1;
        unsigned s0 = 0, s1 = 0;
#pragma unroll
        for (int s = 0; s < SLICES; ++s) {
            unsigned v = cnt_src[(((size_t)s * N_REL + r) * 2 + ch) * CHUNKW + i];
            s0 += v & 0xffffu;
            s1 += v >> 16;
        }
        size_t nidx = (size_t)r * N_NODES + 2 * pair;
        nsrc[nidx]     = s0 ? rsqrtf((float)s0) : 0.0f;
        nsrc[nidx + 1] = s1 ? rsqrtf((float)s1) : 0.0f;
        // fold the 1/R = 0.25 mean factor into ndst
        ndst[nidx]     = d0 ? 0.25f * rsqrtf((float)d0) : 0.0f;
        ndst[nidx + 1] = d1 ? 0.25f * rsqrtf((float)d1) : 0.0f;
    }
    __shared__ int sh[256];
    int dsum = d0 + d1;
    sh[t] = dsum;
    __syncthreads();
#pragma unroll
    for (int off = 1; off < 256; off <<= 1) {
        int v = (t >= off) ? sh[t - off] : 0;
        __syncthreads();
        sh[t] += v;
        __syncthreads();
    }
    if (pair < CHUNKN) {
        int base = sh[t] - dsum;
        offs[r * (N_NODES + 1) + 2 * pair]     = base;
        offs[r * (N_NODES + 1) + 2 * pair + 1] = base + d0;
    }
    if (t == 255) bsum[r * NBLK2 + blk] = sh[255];
}

// ---- 2b) finalize: scan block sums + finalize offs (fused) ------------------
__global__ __launch_bounds__(256) void finalize_kernel(int* __restrict__ bsum,
                                                       int* __restrict__ offs) {
    const int r = blockIdx.x;
    const int t = threadIdx.x;
    __shared__ int sh[256];
    __shared__ int base[NBLK2];
    int v = (t < NBLK2) ? bsum[r * NBLK2 + t] : 0;
    sh[t] = v;
    __syncthreads();
#pragma unroll
    for (int off = 1; off < 256; off <<= 1) {
        int u = (t >= off) ? sh[t - off] : 0;
        __syncthreads();
        sh[t] += u;
        __syncthreads();
    }
    if (t < NBLK2) base[t] = sh[t] - v;        // exclusive block base
    __syncthreads();
    for (int j = t; j < N_NODES; j += 256)
        offs[r * (N_NODES + 1) + j] += base[j >> 9];
    if (t == 0) offs[r * (N_NODES + 1) + N_NODES] = N_EDGES;
}

// ---- 3) place: seeded LDS histogram replay -> u32 records -------------------
__global__ __launch_bounds__(512) void place_kernel(
    const int* __restrict__ src, const int* __restrict__ dst,
    const unsigned* __restrict__ cnt_dst,     // slice prefixes (packed u16)
    const float* __restrict__ nsrc,
    const int* __restrict__ offs, unsigned* __restrict__ csr_rec) {
    const int s = blockIdx.x;
    const int ch = blockIdx.y;
    const int r = blockIdx.z;
    const int t = threadIdx.x;
    __shared__ unsigned bins[CHUNKW];
    const unsigned* seed = cnt_dst + (((size_t)s * N_REL + r) * 2 + ch) * CHUNKW;
    for (int i = t; i < CHUNKW; i += 512) bins[i] = seed[i];
    __syncthreads();
    const int c0 = ch * CHUNKN;
    for (int e = s * EPS + t; e < (s + 1) * EPS; e += 512) {
        int d = dst[(size_t)r * N_EDGES + e];
        unsigned dl = (unsigned)(d - c0);
        if (dl < CHUNKN) {
            unsigned sh = (dl & 1) * 16;
            unsigned old = atomicAdd(&bins[dl >> 1], 1u << sh);
            int pos = (int)((old >> sh) & 0xffffu);
            int sg = src[(size_t)r * N_EDGES + e];
            int p = offs[r * (N_NODES + 1) + d] + pos;
            csr_rec[(size_t)r * N_EDGES + p] =
                (unsigned)sg | ((unsigned)f2bf(nsrc[(size_t)r * N_NODES + sg]) << 16);
        }
    }
}

// ---- 4) gather1: XCD-pinned column groups -----------------------------------
// 50000 blocks; block b: colgroup cg=(b&7)>>1 pinned to an XCD pair (%8 law),
// node-block i=((b>>3)<<1)|(b&1); wave=node, lane=(eg 0..15)x(cs 0..3 x 16B).
// Each XCD pair touches only a 3.2 MB slice of the 12.8 MB emb table.
__global__ __launch_bounds__(256) void gather1_kernel(
    const unsigned short* __restrict__ xb,    // [N][128] bf16
    const unsigned* __restrict__ csr_rec,     // [R][E] u32 (src:16|w:16)
    const int* __restrict__ offs,
    const float* __restrict__ ndst,           // pre-scaled by 0.25
    unsigned* __restrict__ aggb) {            // [N][256] u32 (= 512 bf16)
    const int b = blockIdx.x;
    const int cg = (b & 7) >> 1;              // column group 0..3 (64 B each)
    const int i = ((b >> 3) << 1) | (b & 1);  // node-block 0..12499
    const int wave = threadIdx.x >> 6;
    const int lane = threadIdx.x & 63;
    const int d = i * 4 + wave;
    if (d >= N_NODES) return;
    const int cs = lane & 3;                  // 16B segment within 64B
    const int eg = lane >> 2;                 // edge depth 0..15
    const uint4* x4 = (const uint4*)xb;       // row = 16 uint4
    for (int r = 0; r < N_REL; ++r) {
        int e0 = offs[r * (N_NODES + 1) + d];
        int e1 = offs[r * (N_NODES + 1) + d + 1];
        const unsigned* rec = csr_rec + (size_t)r * N_EDGES;
        float a[8];
#pragma unroll
        for (int j = 0; j < 8; ++j) a[j] = 0.0f;
        for (int e = e0; e < e1; e += 16) {
            int ee = e + eg;
            bool ok = ee < e1;
            unsigned rc = rec[ok ? ee : e0];
            float w = ok ? bf2f(rc >> 16) : 0.0f;
            uint4 v = x4[(size_t)(rc & 0xffffu) * 16 + cg * 4 + cs];
            a[0] += bf2f(v.x & 0xffffu) * w;
            a[1] += bf2f(v.x >> 16) * w;
            a[2] += bf2f(v.y & 0xffffu) * w;
            a[3] += bf2f(v.y >> 16) * w;
            a[4] += bf2f(v.z & 0xffffu) * w;
            a[5] += bf2f(v.z >> 16) * w;
            a[6] += bf2f(v.w & 0xffffu) * w;
            a[7] += bf2f(v.w >> 16) * w;
        }
#pragma unroll
        for (int j = 0; j < 8; ++j) {         // combine 16 edge groups (bits 2..5)
            a[j] += __shfl_xor(a[j], 4, 64);
            a[j] += __shfl_xor(a[j], 8, 64);
            a[j] += __shfl_xor(a[j], 16, 64);
            a[j] += __shfl_xor(a[j], 32, 64);
        }
        float sc = ndst[(size_t)r * N_NODES + d];
        if (eg == 0) {
            uint4 o;
            o.x = (unsigned)f2bf(a[0] * sc) | ((unsigned)f2bf(a[1] * sc) << 16);
            o.y = (unsigned)f2bf(a[2] * sc) | ((unsigned)f2bf(a[3] * sc) << 16);
            o.z = (unsigned)f2bf(a[4] * sc) | ((unsigned)f2bf(a[5] * sc) << 16);
            o.w = (unsigned)f2bf(a[6] * sc) | ((unsigned)f2bf(a[7] * sc) << 16);
            *(uint4*)&aggb[(size_t)d * 256 + r * 64 + cg * 16 + cs * 4] = o;
        }
    }
}

// ---- 5) gemm1 MFMA: h1b = aggb[.][512](bf16) @ W1p + bias -> bf16 -----------
__global__ __launch_bounds__(256) void gemm1_mfma(
    const unsigned short* __restrict__ aggb,  // [N][512] bf16
    const unsigned short* __restrict__ W1p,
    const float* __restrict__ b1,
    unsigned short* __restrict__ h1b,         // [N][128] bf16
    int nnodes) {
    const int t = threadIdx.x;
    const int w = t >> 6, l = t & 63;
    const int row_base = blockIdx.x * 64 + w * 16;
    const int m = l & 15, kg = l >> 4;
    float4v acc[8];
#pragma unroll
    for (int ct = 0; ct < 8; ++ct) acc[ct] = (float4v){0.f, 0.f, 0.f, 0.f};
    const int arow = row_base + m;
    const bool aok = (arow < nnodes);
    const short8v* ap = (const short8v*)(aggb + (size_t)arow * 512 + kg * 8);
    const short8v* bp = (const short8v*)W1p;
#pragma unroll
    for (int ks = 0; ks < 16; ++ks) {
        short8v a = (short8v){0,0,0,0,0,0,0,0};
        if (aok) a = ap[ks * 4];               // +32 bf16 per ks
#pragma unroll
        for (int ct = 0; ct < 8; ++ct) {
            short8v b = bp[(ks * 8 + ct) * 64 + l];
            acc[ct] = __builtin_amdgcn_mfma_f32_16x16x32_bf16(a, b, acc[ct], 0, 0, 0);
        }
    }
    const int orow0 = row_base + kg * 4;
#pragma unroll
    for (int ct = 0; ct < 8; ++ct) {
        int c = ct * 16 + m;
        float bias = 0.25f * (b1[c] + b1[128 + c] + b1[256 + c] + b1[384 + c]);
#pragma unroll
        for (int i = 0; i < 4; ++i) {
            int row = orow0 + i;
            if (row < nnodes)
                h1b[(size_t)row * 128 + c] = f2bf(acc[ct][i] + bias);
        }
    }
}

// ---- 6) gemm2 MFMA: p2b = rowscale(h1b[.][128] @ W2p) -> bf16 ---------------
__global__ __launch_bounds__(256) void gemm2_mfma(
    const unsigned short* __restrict__ h1b,   // [N][128] bf16
    const unsigned short* __restrict__ W2p,
    const float* __restrict__ nsrc,           // [4][N]
    unsigned short* __restrict__ p2b) {       // [N][256] bf16
    const int t = threadIdx.x;
    const int w = t >> 6, l = t & 63;
    const int row_base = blockIdx.x * 64 + w * 16;
    const int m = l & 15, kg = l >> 4;
    float4v acc[16];
#pragma unroll
    for (int ct = 0; ct < 16; ++ct) acc[ct] = (float4v){0.f, 0.f, 0.f, 0.f};
    const int arow = row_base + m;
    const bool aok = (arow < N_NODES);
    const short8v* ap = (const short8v*)(h1b + (size_t)arow * 128 + kg * 8);
    const short8v* bp = (const short8v*)W2p;
#pragma unroll
    for (int ks = 0; ks < 4; ++ks) {
        short8v a = (short8v){0,0,0,0,0,0,0,0};
        if (aok) a = ap[ks * 4];
#pragma unroll
        for (int ct = 0; ct < 16; ++ct) {
            short8v b = bp[(ks * 16 + ct) * 64 + l];
            acc[ct] = __builtin_amdgcn_mfma_f32_16x16x32_bf16(a, b, acc[ct], 0, 0, 0);
        }
    }
    const int orow0 = row_base + kg * 4;
#pragma unroll
    for (int ct = 0; ct < 16; ++ct) {
        int c = ct * 16 + m;
        int r = c >> 6;
#pragma unroll
        for (int i = 0; i < 4; ++i) {
            int row = orow0 + i;
            if (row < N_NODES)
                p2b[(size_t)row * 256 + c] = f2bf(acc[ct][i] * nsrc[(size_t)r * N_NODES + row]);
        }
    }
}

// ---- 7) gather2: 8 lanes/slice (uint4), 8 edges per wave-load ---------------
__global__ __launch_bounds__(256) void gather2_kernel(
    const unsigned short* __restrict__ p2b,   // [N][256] bf16
    const unsigned* __restrict__ csr_rec,
    const int* __restrict__ offs,
    const float* __restrict__ ndst,           // pre-scaled by 0.25
    const float* __restrict__ b2,
    float* __restrict__ out) {
    int wid = (blockIdx.x * 256 + threadIdx.x) >> 6;
    int lane = threadIdx.x & 63;
    if (wid >= N_NODES) return;
    int d = wid;
    const int eg = lane >> 3;                 // edge group 0..7
    const int cs = lane & 7;                  // bf16 cols cs*8..+7 of 64-col slice
    const uint4* p4 = (const uint4*)p2b;      // row = 32 uint4
    float tot[8];
#pragma unroll
    for (int j = 0; j < 8; ++j) tot[j] = 0.0f;
    for (int r = 0; r < N_REL; ++r) {
        int e0 = offs[r * (N_NODES + 1) + d];
        int e1 = offs[r * (N_NODES + 1) + d + 1];
        const unsigned* rec = csr_rec + (size_t)r * N_EDGES;
        float a[8];
#pragma unroll
        for (int j = 0; j < 8; ++j) a[j] = 0.0f;
        for (int e = e0; e < e1; e += 8) {
            int ee = e + eg;
            bool ok = ee < e1;
            unsigned rc = rec[ok ? ee : e0];
            float w = ok ? 1.0f : 0.0f;
            uint4 v = p4[(size_t)(rc & 0xffffu) * 32 + r * 8 + cs];
            a[0] += bf2f(v.x & 0xffffu) * w;
            a[1] += bf2f(v.x >> 16) * w;
            a[2] += bf2f(v.y & 0xffffu) * w;
            a[3] += bf2f(v.y >> 16) * w;
            a[4] += bf2f(v.z & 0xffffu) * w;
            a[5] += bf2f(v.z >> 16) * w;
            a[6] += bf2f(v.w & 0xffffu) * w;
            a[7] += bf2f(v.w >> 16) * w;
        }
        float nd = ndst[(size_t)r * N_NODES + d];
#pragma unroll
        for (int j = 0; j < 8; ++j) tot[j] += a[j] * nd;
    }
#pragma unroll
    for (int j = 0; j < 8; ++j) {
        tot[j] += __shfl_xor(tot[j], 8, 64);
        tot[j] += __shfl_xor(tot[j], 16, 64);
        tot[j] += __shfl_xor(tot[j], 32, 64);
    }
    if (eg == 0) {
        float o[8];
#pragma unroll
        for (int j = 0; j < 8; ++j) {
            int c = cs * 8 + j;
            o[j] = tot[j] + 0.25f * (b2[c] + b2[64 + c] + b2[128 + c] + b2[192 + c]);
        }
        *(float4*)&out[(size_t)d * OUTD + cs * 8]     = *(float4*)&o[0];
        *(float4*)&out[(size_t)d * OUTD + cs * 8 + 4] = *(float4*)&o[4];
    }
}

// ----------------------------------------------------------------- launch ---
extern "C" void kernel_launch(void* const* d_in, const int* in_sizes, int n_in,
                              void* d_out, int out_size, void* d_ws, size_t ws_size,
                              hipStream_t stream) {
    const int* src = (const int*)d_in[1];
    const int* dst = (const int*)d_in[2];
    const float* emb = (const float*)d_in[3];
    const float* W1 = (const float*)d_in[4];
    const float* b1 = (const float*)d_in[5];
    const float* W2 = (const float*)d_in[6];
    const float* b2 = (const float*)d_in[7];
    float* out = (float*)d_out;

    char* p = (char*)d_ws;
    auto alloc = [&](size_t bytes) -> void* {
        void* q = (void*)p;
        p += (bytes + 255) & ~(size_t)255;
        return q;
    };
    // ---- persistent (~37 MB)
    int* offs = (int*)alloc((size_t)N_REL * (N_NODES + 1) * 4);
    int* bsum = (int*)alloc((size_t)N_REL * NBLK2 * 4);
    float* nsrc = (float*)alloc((size_t)N_REL * N_NODES * 4);
    float* ndst = (float*)alloc((size_t)N_REL * N_NODES * 4);
    unsigned* csr_rec = (unsigned*)alloc((size_t)N_REL * N_EDGES * 4);        // 8 MB
    unsigned short* h1b = (unsigned short*)alloc((size_t)N_NODES * HID * 2);  // 12.8 MB
    unsigned short* embb = (unsigned short*)alloc((size_t)N_NODES * EMB * 2); // 12.8 MB
    unsigned short* W1p = (unsigned short*)alloc((size_t)16 * 8 * 64 * 8 * 2);  // 128 KB
    unsigned short* W2p = (unsigned short*)alloc((size_t)4 * 16 * 64 * 8 * 2);  // 64 KB
    // ---- transient region X: CSR-count buffers, then aggb, then p2b (aliased)
    char* X = p;
    unsigned* cnt_dst = (unsigned*)X;                                         // 12.8 MB
    unsigned* cnt_src = cnt_dst + (size_t)SLICES * N_REL * 2 * CHUNKW;        // 12.8 MB
    unsigned* aggb = (unsigned*)X;              // [N][256] u32, 51.2 MB, after place
    unsigned short* p2b = (unsigned short*)X;   // [N][256] bf16, 25.6 MB, after gemm1

    // one-time conversions/packs (independent of CSR build)
    prep_kernel<<<6298, 256, 0, stream>>>(emb, W1, W2, embb, W1p, W2p);

    // CSR build: LDS histograms -> scan -> seeded place (no global atomics)
    hist_kernel<<<dim3(SLICES, 2, 8), 512, 0, stream>>>(src, dst, cnt_dst, cnt_src);
    scan1_kernel<<<dim3(NBLK2, N_REL), 256, 0, stream>>>(cnt_dst, cnt_src, nsrc, ndst, offs, bsum);
    finalize_kernel<<<N_REL, 256, 0, stream>>>(bsum, offs);
    place_kernel<<<dim3(SLICES, 2, N_REL), 512, 0, stream>>>(
        src, dst, cnt_dst, nsrc, offs, csr_rec);

    // layer 1: embb -> aggb (bf16, XCD-pinned colgroups) -> h1b (MFMA)
    gather1_kernel<<<50000, 256, 0, stream>>>(embb, csr_rec, offs, ndst, aggb);
    gemm1_mfma<<<(N_NODES + 63) / 64, 256, 0, stream>>>(
        (const unsigned short*)aggb, W1p, b1, h1b, N_NODES);
    // layer 2: h1b -> p2b (MFMA, project-first, bf16) -> out
    gemm2_mfma<<<(N_NODES + 63) / 64, 256, 0, stream>>>(h1b, W2p, nsrc, p2b);
    gather2_kernel<<<(N_NODES * 64 + 255) / 256, 256, 0, stream>>>(
        p2b, csr_rec, offs, ndst, b2, out);
}

// Round 16
// 315.310 us; speedup vs baseline: 1.5525x; 1.5525x over previous
//
#include <hip/hip_runtime.h>
#include <hip/hip_bf16.h>

#define N_NODES 50000
#define N_REL   4
#define N_EDGES 500000
#define EMB     128
#define HID     128
#define OUTD    64
#define SLICES  32
#define EPS     (N_EDGES / SLICES)   // 15625 edges per slice (exact)
#define CHUNKN  25000                // nodes per chunk (2 chunks)
#define CHUNKW  12500                // packed u32 per chunk (2 x u16)
#define NBLK2   98                   // ceil(50000 / 512) scan1 blocks per rel

typedef __attribute__((ext_vector_type(8))) short short8v;   // 8 bf16 = 4 VGPR
typedef __attribute__((ext_vector_type(4))) float float4v;   // mfma acc

__device__ __forceinline__ unsigned short f2bf(float f) {   // RNE bf16 pack
    unsigned u = __float_as_uint(f);
    u = (u + 0x7fffu + ((u >> 16) & 1u)) >> 16;
    return (unsigned short)u;
}
__device__ __forceinline__ float bf2f(unsigned v) {
    return __uint_as_float(v << 16);
}

// ---- 0) prep: fused emb->bf16 cvt + W1/W2 fragment packs --------------------
__global__ void prep_kernel(const float* __restrict__ emb,
                            const float* __restrict__ W1,
                            const float* __restrict__ W2,
                            unsigned short* __restrict__ embb,
                            unsigned short* __restrict__ W1p,
                            unsigned short* __restrict__ W2p) {
    int b = blockIdx.x, t = threadIdx.x;
    if (b < 6250) {                            // cvt: 1.6M float4
        int i = b * 256 + t;
        float4 v = *(const float4*)&emb[(size_t)i * 4];
        ushort4 o;
        o.x = f2bf(v.x); o.y = f2bf(v.y); o.z = f2bf(v.z); o.w = f2bf(v.w);
        *(ushort4*)&embb[(size_t)i * 4] = o;
    } else if (b < 6282) {                     // packW1: 8192 fragments
        int idx = (b - 6250) * 256 + t;
        int l = idx & 63, ct = (idx >> 6) & 7, ks = idx >> 9;
        int n = ct * 16 + (l & 15);
        int k0 = ks * 32 + (l >> 4) * 8;
        ushort4 o0, o1;
        o0.x = f2bf(W1[(size_t)(k0 + 0) * 128 + n]);
        o0.y = f2bf(W1[(size_t)(k0 + 1) * 128 + n]);
        o0.z = f2bf(W1[(size_t)(k0 + 2) * 128 + n]);
        o0.w = f2bf(W1[(size_t)(k0 + 3) * 128 + n]);
        o1.x = f2bf(W1[(size_t)(k0 + 4) * 128 + n]);
        o1.y = f2bf(W1[(size_t)(k0 + 5) * 128 + n]);
        o1.z = f2bf(W1[(size_t)(k0 + 6) * 128 + n]);
        o1.w = f2bf(W1[(size_t)(k0 + 7) * 128 + n]);
        *(ushort4*)&W1p[(size_t)idx * 8]     = o0;
        *(ushort4*)&W1p[(size_t)idx * 8 + 4] = o1;
    } else {                                   // packW2: 4096 fragments
        int idx = (b - 6282) * 256 + t;
        int l = idx & 63, ct = (idx >> 6) & 15, ks = idx >> 10;
        int n = ct * 16 + (l & 15);
        int r = n >> 6, cc = n & 63;
        int k0 = ks * 32 + (l >> 4) * 8;
        ushort4 o0, o1;
        o0.x = f2bf(W2[((size_t)r * 128 + k0 + 0) * 64 + cc]);
        o0.y = f2bf(W2[((size_t)r * 128 + k0 + 1) * 64 + cc]);
        o0.z = f2bf(W2[((size_t)r * 128 + k0 + 2) * 64 + cc]);
        o0.w = f2bf(W2[((size_t)r * 128 + k0 + 3) * 64 + cc]);
        o1.x = f2bf(W2[((size_t)r * 128 + k0 + 4) * 64 + cc]);
        o1.y = f2bf(W2[((size_t)r * 128 + k0 + 5) * 64 + cc]);
        o1.z = f2bf(W2[((size_t)r * 128 + k0 + 6) * 64 + cc]);
        o1.w = f2bf(W2[((size_t)r * 128 + k0 + 7) * 64 + cc]);
        *(ushort4*)&W2p[(size_t)idx * 8]     = o0;
        *(ushort4*)&W2p[(size_t)idx * 8 + 4] = o1;
    }
}

// ---- 1) hist: per-slice LDS count histograms (no global atomics) ------------
__global__ __launch_bounds__(512) void hist_kernel(
    const int* __restrict__ src, const int* __restrict__ dst,
    unsigned* __restrict__ cnt_dst, unsigned* __restrict__ cnt_src) {
    const int s = blockIdx.x;
    const int ch = blockIdx.y;
    const int z = blockIdx.z;
    const int r = z & 3;
    const bool do_dst = (z < 4);
    const int t = threadIdx.x;
    __shared__ unsigned bins[CHUNKW];          // 50 KB: 25000 x u16 packed
    for (int i = t; i < CHUNKW; i += 512) bins[i] = 0;
    __syncthreads();
    const int* col = do_dst ? dst : src;
    const int c0 = ch * CHUNKN;
    for (int e = s * EPS + t; e < (s + 1) * EPS; e += 512) {
        unsigned dl = (unsigned)(col[(size_t)r * N_EDGES + e] - c0);
        if (dl < CHUNKN)
            atomicAdd(&bins[dl >> 1], 1u << ((dl & 1) * 16));
    }
    __syncthreads();
    unsigned* out = (do_dst ? cnt_dst : cnt_src)
                  + (((size_t)s * N_REL + r) * 2 + ch) * CHUNKW;
    for (int i = t; i < CHUNKW; i += 512) out[i] = bins[i];
}

// ---- 2a) scan1: slice-reduce + in-place slice-prefix + norms + block scan ---
__global__ __launch_bounds__(256) void scan1_kernel(
    unsigned* __restrict__ cnt_dst, const unsigned* __restrict__ cnt_src,
    float* __restrict__ nsrc, float* __restrict__ ndst,
    int* __restrict__ offs, int* __restrict__ bsum) {
    const int r = blockIdx.y;
    const int blk = blockIdx.x;
    const int t = threadIdx.x;
    const int pair = blk * 256 + t;            // 0 .. 24999
    int d0 = 0, d1 = 0;
    if (pair < CHUNKN) {
        int ch = (2 * pair) / CHUNKN;          // 0 or 1
        int i = pair - ch * CHUNKW;
        unsigned run0 = 0, run1 = 0;
#pragma unroll
        for (int s = 0; s < SLICES; ++s) {
            size_t idx = (((size_t)s * N_REL + r) * 2 + ch) * CHUNKW + i;
            unsigned v = cnt_dst[idx];
            cnt_dst[idx] = run0 | (run1 << 16); // exclusive slice-prefix (packed)
            run0 += v & 0xffffu;
            run1 += v >> 16;
        }
        d0 = (int)run0; d1 = (int)run1;
        unsigned s0 = 0, s1 = 0;
#pragma unroll
        for (int s = 0; s < SLICES; ++s) {
            unsigned v = cnt_src[(((size_t)s * N_REL + r) * 2 + ch) * CHUNKW + i];
            s0 += v & 0xffffu;
            s1 += v >> 16;
        }
        size_t nidx = (size_t)r * N_NODES + 2 * pair;
        nsrc[nidx]     = s0 ? rsqrtf((float)s0) : 0.0f;
        nsrc[nidx + 1] = s1 ? rsqrtf((float)s1) : 0.0f;
        // fold the 1/R = 0.25 mean factor into ndst
        ndst[nidx]     = d0 ? 0.25f * rsqrtf((float)d0) : 0.0f;
        ndst[nidx + 1] = d1 ? 0.25f * rsqrtf((float)d1) : 0.0f;
    }
    __shared__ int sh[256];
    int dsum = d0 + d1;
    sh[t] = dsum;
    __syncthreads();
#pragma unroll
    for (int off = 1; off < 256; off <<= 1) {
        int v = (t >= off) ? sh[t - off] : 0;
        __syncthreads();
        sh[t] += v;
        __syncthreads();
    }
    if (pair < CHUNKN) {
        int base = sh[t] - dsum;
        offs[r * (N_NODES + 1) + 2 * pair]     = base;
        offs[r * (N_NODES + 1) + 2 * pair + 1] = base + d0;
    }
    if (t == 255) bsum[r * NBLK2 + blk] = sh[255];
}

// ---- 2b) finalize: scan block sums + finalize offs (fused) ------------------
__global__ __launch_bounds__(256) void finalize_kernel(int* __restrict__ bsum,
                                                       int* __restrict__ offs) {
    const int r = blockIdx.x;
    const int t = threadIdx.x;
    __shared__ int sh[256];
    __shared__ int base[NBLK2];
    int v = (t < NBLK2) ? bsum[r * NBLK2 + t] : 0;
    sh[t] = v;
    __syncthreads();
#pragma unroll
    for (int off = 1; off < 256; off <<= 1) {
        int u = (t >= off) ? sh[t - off] : 0;
        __syncthreads();
        sh[t] += u;
        __syncthreads();
    }
    if (t < NBLK2) base[t] = sh[t] - v;        // exclusive block base
    __syncthreads();
    for (int j = t; j < N_NODES; j += 256)
        offs[r * (N_NODES + 1) + j] += base[j >> 9];
    if (t == 0) offs[r * (N_NODES + 1) + N_NODES] = N_EDGES;
}

// ---- 3) place: seeded LDS histogram replay -> u32 records -------------------
__global__ __launch_bounds__(512) void place_kernel(
    const int* __restrict__ src, const int* __restrict__ dst,
    const unsigned* __restrict__ cnt_dst,     // slice prefixes (packed u16)
    const float* __restrict__ nsrc,
    const int* __restrict__ offs, unsigned* __restrict__ csr_rec) {
    const int s = blockIdx.x;
    const int ch = blockIdx.y;
    const int r = blockIdx.z;
    const int t = threadIdx.x;
    __shared__ unsigned bins[CHUNKW];
    const unsigned* seed = cnt_dst + (((size_t)s * N_REL + r) * 2 + ch) * CHUNKW;
    for (int i = t; i < CHUNKW; i += 512) bins[i] = seed[i];
    __syncthreads();
    const int c0 = ch * CHUNKN;
    for (int e = s * EPS + t; e < (s + 1) * EPS; e += 512) {
        int d = dst[(size_t)r * N_EDGES + e];
        unsigned dl = (unsigned)(d - c0);
        if (dl < CHUNKN) {
            unsigned sh = (dl & 1) * 16;
            unsigned old = atomicAdd(&bins[dl >> 1], 1u << sh);
            int pos = (int)((old >> sh) & 0xffffu);
            int sg = src[(size_t)r * N_EDGES + e];
            int p = offs[r * (N_NODES + 1) + d] + pos;
            csr_rec[(size_t)r * N_EDGES + p] =
                (unsigned)sg | ((unsigned)f2bf(nsrc[(size_t)r * N_NODES + sg]) << 16);
        }
    }
}

// ---- 4) gather1: 16 lanes/row (uint4), 4 edges per wave-load (r14 form) -----
__global__ __launch_bounds__(256) void gather1_kernel(
    const unsigned short* __restrict__ xb,    // [N][128] bf16
    const unsigned* __restrict__ csr_rec,     // [R][E] u32 (src:16|w:16)
    const int* __restrict__ offs,
    const float* __restrict__ ndst,           // pre-scaled by 0.25
    unsigned* __restrict__ aggb) {            // [N][256] u32 (= 512 bf16)
    int wid = (blockIdx.x * 256 + threadIdx.x) >> 6;
    int lane = threadIdx.x & 63;
    if (wid >= N_NODES) return;
    int d = wid;
    const int eg = lane >> 4;                 // edge group 0..3
    const int cs = lane & 15;                 // col segment: bf16 cols cs*8..+7
    const uint4* x4 = (const uint4*)xb;       // row = 16 uint4
    unsigned* arow = aggb + (size_t)wid * (N_REL * 64);
    for (int r = 0; r < N_REL; ++r) {
        int e0 = offs[r * (N_NODES + 1) + d];
        int e1 = offs[r * (N_NODES + 1) + d + 1];
        const unsigned* rec = csr_rec + (size_t)r * N_EDGES;
        float a[8];
#pragma unroll
        for (int j = 0; j < 8; ++j) a[j] = 0.0f;
        for (int e = e0; e < e1; e += 4) {
            int ee = e + eg;
            bool ok = ee < e1;
            unsigned rc = rec[ok ? ee : e0];
            float w = ok ? bf2f(rc >> 16) : 0.0f;
            uint4 v = x4[(size_t)(rc & 0xffffu) * 16 + cs];
            a[0] += bf2f(v.x & 0xffffu) * w;
            a[1] += bf2f(v.x >> 16) * w;
            a[2] += bf2f(v.y & 0xffffu) * w;
            a[3] += bf2f(v.y >> 16) * w;
            a[4] += bf2f(v.z & 0xffffu) * w;
            a[5] += bf2f(v.z >> 16) * w;
            a[6] += bf2f(v.w & 0xffffu) * w;
            a[7] += bf2f(v.w >> 16) * w;
        }
#pragma unroll
        for (int j = 0; j < 8; ++j) {         // combine 4 edge groups (bits 4,5)
            a[j] += __shfl_xor(a[j], 16, 64);
            a[j] += __shfl_xor(a[j], 32, 64);
        }
        float sc = ndst[(size_t)r * N_NODES + d];
        if (eg == 0) {
            uint4 o;
            o.x = (unsigned)f2bf(a[0] * sc) | ((unsigned)f2bf(a[1] * sc) << 16);
            o.y = (unsigned)f2bf(a[2] * sc) | ((unsigned)f2bf(a[3] * sc) << 16);
            o.z = (unsigned)f2bf(a[4] * sc) | ((unsigned)f2bf(a[5] * sc) << 16);
            o.w = (unsigned)f2bf(a[6] * sc) | ((unsigned)f2bf(a[7] * sc) << 16);
            *(uint4*)&arow[r * 64 + cs * 4] = o;
        }
    }
}

// ---- 5) gemm1 MFMA: h1b = aggb[.][512](bf16) @ W1p + bias -> bf16 -----------
__global__ __launch_bounds__(256) void gemm1_mfma(
    const unsigned short* __restrict__ aggb,  // [N][512] bf16
    const unsigned short* __restrict__ W1p,
    const float* __restrict__ b1,
    unsigned short* __restrict__ h1b,         // [N][128] bf16
    int nnodes) {
    const int t = threadIdx.x;
    const int w = t >> 6, l = t & 63;
    const int row_base = blockIdx.x * 64 + w * 16;
    const int m = l & 15, kg = l >> 4;
    float4v acc[8];
#pragma unroll
    for (int ct = 0; ct < 8; ++ct) acc[ct] = (float4v){0.f, 0.f, 0.f, 0.f};
    const int arow = row_base + m;
    const bool aok = (arow < nnodes);
    const short8v* ap = (const short8v*)(aggb + (size_t)arow * 512 + kg * 8);
    const short8v* bp = (const short8v*)W1p;
#pragma unroll
    for (int ks = 0; ks < 16; ++ks) {
        short8v a = (short8v){0,0,0,0,0,0,0,0};
        if (aok) a = ap[ks * 4];               // +32 bf16 per ks
#pragma unroll
        for (int ct = 0; ct < 8; ++ct) {
            short8v b = bp[(ks * 8 + ct) * 64 + l];
            acc[ct] = __builtin_amdgcn_mfma_f32_16x16x32_bf16(a, b, acc[ct], 0, 0, 0);
        }
    }
    const int orow0 = row_base + kg * 4;
#pragma unroll
    for (int ct = 0; ct < 8; ++ct) {
        int c = ct * 16 + m;
        float bias = 0.25f * (b1[c] + b1[128 + c] + b1[256 + c] + b1[384 + c]);
#pragma unroll
        for (int i = 0; i < 4; ++i) {
            int row = orow0 + i;
            if (row < nnodes)
                h1b[(size_t)row * 128 + c] = f2bf(acc[ct][i] + bias);
        }
    }
}

// ---- 6) gemm2 MFMA: p2b = rowscale(h1b[.][128] @ W2p) -> bf16 ---------------
__global__ __launch_bounds__(256) void gemm2_mfma(
    const unsigned short* __restrict__ h1b,   // [N][128] bf16
    const unsigned short* __restrict__ W2p,
    const float* __restrict__ nsrc,           // [4][N]
    unsigned short* __restrict__ p2b) {       // [N][256] bf16
    const int t = threadIdx.x;
    const int w = t >> 6, l = t & 63;
    const int row_base = blockIdx.x * 64 + w * 16;
    const int m = l & 15, kg = l >> 4;
    float4v acc[16];
#pragma unroll
    for (int ct = 0; ct < 16; ++ct) acc[ct] = (float4v){0.f, 0.f, 0.f, 0.f};
    const int arow = row_base + m;
    const bool aok = (arow < N_NODES);
    const short8v* ap = (const short8v*)(h1b + (size_t)arow * 128 + kg * 8);
    const short8v* bp = (const short8v*)W2p;
#pragma unroll
    for (int ks = 0; ks < 4; ++ks) {
        short8v a = (short8v){0,0,0,0,0,0,0,0};
        if (aok) a = ap[ks * 4];
#pragma unroll
        for (int ct = 0; ct < 16; ++ct) {
            short8v b = bp[(ks * 16 + ct) * 64 + l];
            acc[ct] = __builtin_amdgcn_mfma_f32_16x16x32_bf16(a, b, acc[ct], 0, 0, 0);
        }
    }
    const int orow0 = row_base + kg * 4;
#pragma unroll
    for (int ct = 0; ct < 16; ++ct) {
        int c = ct * 16 + m;
        int r = c >> 6;
#pragma unroll
        for (int i = 0; i < 4; ++i) {
            int row = orow0 + i;
            if (row < N_NODES)
                p2b[(size_t)row * 256 + c] = f2bf(acc[ct][i] * nsrc[(size_t)r * N_NODES + row]);
        }
    }
}

// ---- 7) gather2: 8 lanes/slice (uint4), 8 edges per wave-load ---------------
__global__ __launch_bounds__(256) void gather2_kernel(
    const unsigned short* __restrict__ p2b,   // [N][256] bf16
    const unsigned* __restrict__ csr_rec,
    const int* __restrict__ offs,
    const float* __restrict__ ndst,           // pre-scaled by 0.25
    const float* __restrict__ b2,
    float* __restrict__ out) {
    int wid = (blockIdx.x * 256 + threadIdx.x) >> 6;
    int lane = threadIdx.x & 63;
    if (wid >= N_NODES) return;
    int d = wid;
    const int eg = lane >> 3;                 // edge group 0..7
    const int cs = lane & 7;                  // bf16 cols cs*8..+7 of 64-col slice
    const uint4* p4 = (const uint4*)p2b;      // row = 32 uint4
    float tot[8];
#pragma unroll
    for (int j = 0; j < 8; ++j) tot[j] = 0.0f;
    for (int r = 0; r < N_REL; ++r) {
        int e0 = offs[r * (N_NODES + 1) + d];
        int e1 = offs[r * (N_NODES + 1) + d + 1];
        const unsigned* rec = csr_rec + (size_t)r * N_EDGES;
        float a[8];
#pragma unroll
        for (int j = 0; j < 8; ++j) a[j] = 0.0f;
        for (int e = e0; e < e1; e += 8) {
            int ee = e + eg;
            bool ok = ee < e1;
            unsigned rc = rec[ok ? ee : e0];
            float w = ok ? 1.0f : 0.0f;
            uint4 v = p4[(size_t)(rc & 0xffffu) * 32 + r * 8 + cs];
            a[0] += bf2f(v.x & 0xffffu) * w;
            a[1] += bf2f(v.x >> 16) * w;
            a[2] += bf2f(v.y & 0xffffu) * w;
            a[3] += bf2f(v.y >> 16) * w;
            a[4] += bf2f(v.z & 0xffffu) * w;
            a[5] += bf2f(v.z >> 16) * w;
            a[6] += bf2f(v.w & 0xffffu) * w;
            a[7] += bf2f(v.w >> 16) * w;
        }
        float nd = ndst[(size_t)r * N_NODES + d];
#pragma unroll
        for (int j = 0; j < 8; ++j) tot[j] += a[j] * nd;
    }
#pragma unroll
    for (int j = 0; j < 8; ++j) {
        tot[j] += __shfl_xor(tot[j], 8, 64);
        tot[j] += __shfl_xor(tot[j], 16, 64);
        tot[j] += __shfl_xor(tot[j], 32, 64);
    }
    if (eg == 0) {
        float o[8];
#pragma unroll
        for (int j = 0; j < 8; ++j) {
            int c = cs * 8 + j;
            o[j] = tot[j] + 0.25f * (b2[c] + b2[64 + c] + b2[128 + c] + b2[192 + c]);
        }
        *(float4*)&out[(size_t)d * OUTD + cs * 8]     = *(float4*)&o[0];
        *(float4*)&out[(size_t)d * OUTD + cs * 8 + 4] = *(float4*)&o[4];
    }
}

// ----------------------------------------------------------------- launch ---
extern "C" void kernel_launch(void* const* d_in, const int* in_sizes, int n_in,
                              void* d_out, int out_size, void* d_ws, size_t ws_size,
                              hipStream_t stream) {
    const int* src = (const int*)d_in[1];
    const int* dst = (const int*)d_in[2];
    const float* emb = (const float*)d_in[3];
    const float* W1 = (const float*)d_in[4];
    const float* b1 = (const float*)d_in[5];
    const float* W2 = (const float*)d_in[6];
    const float* b2 = (const float*)d_in[7];
    float* out = (float*)d_out;

    char* p = (char*)d_ws;
    auto alloc = [&](size_t bytes) -> void* {
        void* q = (void*)p;
        p += (bytes + 255) & ~(size_t)255;
        return q;
    };
    // ---- persistent (~37 MB)
    int* offs = (int*)alloc((size_t)N_REL * (N_NODES + 1) * 4);
    int* bsum = (int*)alloc((size_t)N_REL * NBLK2 * 4);
    float* nsrc = (float*)alloc((size_t)N_REL * N_NODES * 4);
    float* ndst = (float*)alloc((size_t)N_REL * N_NODES * 4);
    unsigned* csr_rec = (unsigned*)alloc((size_t)N_REL * N_EDGES * 4);        // 8 MB
    unsigned short* h1b = (unsigned short*)alloc((size_t)N_NODES * HID * 2);  // 12.8 MB
    unsigned short* embb = (unsigned short*)alloc((size_t)N_NODES * EMB * 2); // 12.8 MB
    unsigned short* W1p = (unsigned short*)alloc((size_t)16 * 8 * 64 * 8 * 2);  // 128 KB
    unsigned short* W2p = (unsigned short*)alloc((size_t)4 * 16 * 64 * 8 * 2);  // 64 KB
    // ---- transient region X: CSR-count buffers, then aggb, then p2b (aliased)
    char* X = p;
    unsigned* cnt_dst = (unsigned*)X;                                         // 12.8 MB
    unsigned* cnt_src = cnt_dst + (size_t)SLICES * N_REL * 2 * CHUNKW;        // 12.8 MB
    unsigned* aggb = (unsigned*)X;              // [N][256] u32, 51.2 MB, after place
    unsigned short* p2b = (unsigned short*)X;   // [N][256] bf16, 25.6 MB, after gemm1

    // one-time conversions/packs (independent of CSR build)
    prep_kernel<<<6298, 256, 0, stream>>>(emb, W1, W2, embb, W1p, W2p);

    // CSR build: LDS histograms -> scan -> seeded place (no global atomics)
    hist_kernel<<<dim3(SLICES, 2, 8), 512, 0, stream>>>(src, dst, cnt_dst, cnt_src);
    scan1_kernel<<<dim3(NBLK2, N_REL), 256, 0, stream>>>(cnt_dst, cnt_src, nsrc, ndst, offs, bsum);
    finalize_kernel<<<N_REL, 256, 0, stream>>>(bsum, offs);
    place_kernel<<<dim3(SLICES, 2, N_REL), 512, 0, stream>>>(
        src, dst, cnt_dst, nsrc, offs, csr_rec);

    // layer 1: embb -> aggb (bf16) -> h1b (MFMA)
    gather1_kernel<<<(N_NODES + 3) / 4, 256, 0, stream>>>(embb, csr_rec, offs, ndst, aggb);
    gemm1_mfma<<<(N_NODES + 63) / 64, 256, 0, stream>>>(
        (const unsigned short*)aggb, W1p, b1, h1b, N_NODES);
    // layer 2: h1b -> p2b (MFMA, project-first, bf16) -> out
    gemm2_mfma<<<(N_NODES + 63) / 64, 256, 0, stream>>>(h1b, W2p, nsrc, p2b);
    gather2_kernel<<<(N_NODES * 64 + 255) / 256, 256, 0, stream>>>(
        p2b, csr_rec, offs, ndst, b2, out);
}